// Round 9
// baseline (126.919 us; speedup 1.0000x reference)
//
#include <hip/hip_runtime.h>
#include <stdint.h>

// DBSCAN-on-voxel-grid, exact port of the JAX reference for batch_size==1.
// Grid 512x512, eps=1.5 => 8-connected adjacency, min_samples=5 (voxels,
// incl. self), clusters with <20 voxels dropped.
// R9: occupied-cell WORKLIST built in k_vox (atomicOr unique-setter) drives
// merge/cb at 32 blocks instead of 1024; lab/cnt initialized lazily for
// occupied cells only (no init dispatch); 64 KB memset. Cell-id union-find
// (R8-verified: rank is monotone in cell id so dense numbering matches).

#define GRIDW 512
#define WPR 16        // bitmap words per row
#define NWORDS 8192   // 512*512/32
#define NONE 0xFFFFFFFFu

// ---- ws layout (uint32 units) ----
#define OFF_OCC    0       // 8192  (zeroed by memset)
#define OFF_ROOTBM 8192    // 8192  (zeroed by memset; cell-bitmap)
#define OFF_NOCC   16384   // 1     (zeroed by memset)
#define FILL_BYTES ((16384 + 1) * 4)
#define OFF_WL     16448   // 8192: worklist of occupied cell ids
#define OFF_KEEPBM 24640   // 8192  (fully written in k_finish)
#define OFF_RPRE   32832   // 8192  (fully written in k_finish)
#define OFF_LAB    41024   // 262144 (occupied entries written in k_vox)
#define OFF_CNT    303168  // 262144 (occupied entries zeroed in k_vox)

// per-position horizontal (west+self+east) 2-bit counts for a row of 32 cells
__device__ __forceinline__ void hsum(uint32_t l, uint32_t c, uint32_t r,
                                     uint32_t& h0, uint32_t& h1) {
  uint32_t Wb = (c << 1) | (l >> 31);
  uint32_t Eb = (c >> 1) | (r << 31);
  h0 = Wb ^ c ^ Eb;
  h1 = (Wb & c) | (Eb & (Wb ^ c));
}

// per-position (sum of three 2-bit row counts) >= 5 (bit-sliced adders)
__device__ __forceinline__ uint32_t ge5(uint32_t a0, uint32_t a1, uint32_t b0,
                                        uint32_t b1, uint32_t c0, uint32_t c1) {
  uint32_t u0 = a0 ^ b0, cy = a0 & b0;
  uint32_t t = a1 ^ b1;
  uint32_t u1 = t ^ cy;
  uint32_t u2 = (a1 & b1) | (cy & t);
  uint32_t v0 = u0 ^ c0, k0 = u0 & c0;
  uint32_t t2 = u1 ^ c1;
  uint32_t v1 = t2 ^ k0;
  uint32_t k1 = (u1 & c1) | (k0 & t2);
  uint32_t v2 = u2 ^ k1;
  uint32_t v3 = u2 & k1;
  return v3 | (v2 & (v1 | v0));  // count in {5..9}
}

// core status of bit0 of the word RIGHT of rows (up,mid,down)
__device__ __forceinline__ uint32_t coreRbit(uint32_t cU, uint32_t rU, uint32_t cM,
                                             uint32_t rM, uint32_t cD, uint32_t rD) {
  if (!(rM & 1u)) return 0u;
  int n = __popc((cU >> 31) | ((rU & 3u) << 1)) +
          __popc((cM >> 31) | ((rM & 3u) << 1)) +
          __popc((cD >> 31) | ((rD & 3u) << 1));
  return n >= 5 ? 1u : 0u;
}

// core status of bit31 of the word LEFT of rows
__device__ __forceinline__ uint32_t coreLbit(uint32_t cU, uint32_t lU, uint32_t cM,
                                             uint32_t lM, uint32_t cD, uint32_t lD) {
  if (!(lM >> 31)) return 0u;
  int n = __popc(((lU >> 30) & 3u) | ((cU & 1u) << 2)) +
          __popc(((lM >> 30) & 3u) | ((cM & 1u) << 2)) +
          __popc(((lD >> 30) & 3u) | ((cD & 1u) << 2));
  return n >= 5 ? 1u : 0u;
}

__device__ __forceinline__ uint32_t aread(uint32_t* p) {
  return __hip_atomic_load(p, __ATOMIC_RELAXED, __HIP_MEMORY_SCOPE_AGENT);
}

// find root with guarded path compression: links only ever DECREASE
// (monotone invariant => no cycles, guaranteed termination).
__device__ __forceinline__ uint32_t findc(uint32_t* L, uint32_t x) {
  uint32_t r = x, p = aread(&L[r]);
  while (p != r) { r = p; p = aread(&L[r]); }
  while (x > r) {
    uint32_t nx = aread(&L[x]);
    if (nx <= r) break;
    atomicCAS(&L[x], nx, r);  // best effort, only writes a smaller value
    x = nx;
  }
  return r;
}

// link larger root under smaller => final root == min core CELL of component
__device__ __forceinline__ void unite(uint32_t* L, uint32_t a, uint32_t b) {
  for (;;) {
    a = findc(L, a);
    b = findc(L, b);
    if (a == b) return;
    uint32_t lo = min(a, b), hi = max(a, b);
    if (atomicCAS(&L[hi], hi, lo) == hi) return;
    a = lo; b = hi;
  }
}

// K1: voxelize; the unique setter of each occupancy bit appends the cell to
// the worklist and lazily inits lab/cnt for that cell.
__global__ void k_vox(const float* __restrict__ pts, uint32_t* __restrict__ ws,
                      int npts) {
  int i = blockIdx.x * 256 + threadIdx.x;
  if (i >= npts) return;
  float x = pts[i * 5 + 1];
  float y = pts[i * 5 + 2];
  int cx = (int)floorf((x - (-51.2f)) / 0.2f);  // identical f32 ops to jnp
  int cy = (int)floorf((y - (-51.2f)) / 0.2f);
  cx = min(max(cx, 0), GRIDW - 1);
  cy = min(max(cy, 0), GRIDW - 1);
  int cell = cy * GRIDW + cx;
  uint32_t old = atomicOr(&ws[OFF_OCC + (cell >> 5)], 1u << (cell & 31));
  if (!((old >> (cell & 31)) & 1)) {
    uint32_t idx = atomicAdd(&ws[OFF_NOCC], 1u);  // wave-aggregated by compiler
    ws[OFF_WL + idx] = (uint32_t)cell;
    ws[OFF_LAB + cell] = (uint32_t)cell;
    ws[OFF_CNT + cell] = 0u;
  }
}

// K2: per occupied cell, union core-core edges (E, S, SE, SW)
__global__ void k_merge(uint32_t* __restrict__ ws) {
  int i = blockIdx.x * 256 + threadIdx.x;
  if (i >= (int)ws[OFF_NOCC]) return;
  int cell = (int)ws[OFF_WL + i];
  const uint32_t* occ = ws + OFF_OCC;
  uint32_t* lab = ws + OFF_LAB;
  int wi = cell >> 5, b = cell & 31, wx = wi & 15, y = cell >> 9;
  uint32_t cB = occ[wi];
  uint32_t lB = wx ? occ[wi - 1] : 0u;
  uint32_t rB = (wx < 15) ? occ[wi + 1] : 0u;
  uint32_t cA = 0, lA = 0, rA = 0, cC = 0, lC = 0, rC = 0;
  if (y > 0) { int w = wi - WPR; cA = occ[w]; lA = wx ? occ[w - 1] : 0u; rA = (wx < 15) ? occ[w + 1] : 0u; }
  if (y < GRIDW - 1) { int w = wi + WPR; cC = occ[w]; lC = wx ? occ[w - 1] : 0u; rC = (wx < 15) ? occ[w + 1] : 0u; }
  uint32_t hA0, hA1, hB0, hB1, hC0, hC1;
  hsum(lA, cA, rA, hA0, hA1); hsum(lB, cB, rB, hB0, hB1); hsum(lC, cC, rC, hC0, hC1);
  uint32_t cmB = ge5(hA0, hA1, hB0, hB1, hC0, hC1) & cB;
  if (!((cmB >> b) & 1)) return;  // not core
  bool eC = (b < 31) ? (((cmB >> (b + 1)) & 1) != 0)
                     : (coreRbit(cA, rA, cB, rB, cC, rC) != 0);
  if (eC) unite(lab, cell, cell + 1);
  if (y < GRIDW - 1) {
    uint32_t cD = 0, lD = 0, rD = 0;
    if (y < GRIDW - 2) { int w = wi + 2 * WPR; cD = occ[w]; lD = wx ? occ[w - 1] : 0u; rD = (wx < 15) ? occ[w + 1] : 0u; }
    uint32_t hD0, hD1;
    hsum(lD, cD, rD, hD0, hD1);
    uint32_t cmS = ge5(hB0, hB1, hC0, hC1, hD0, hD1) & cC;
    if ((cmS >> b) & 1) unite(lab, cell, cell + GRIDW);
    bool seC = (b < 31) ? (((cmS >> (b + 1)) & 1) != 0)
                        : (coreRbit(cB, rB, cC, rC, cD, rD) != 0);
    if (seC) unite(lab, cell, cell + GRIDW + 1);
    bool swC = (b > 0) ? (((cmS >> (b - 1)) & 1) != 0)
                       : (coreLbit(cB, lB, cC, lC, cD, lD) != 0);
    if (swC) unite(lab, cell, cell + GRIDW - 1);
  }
}

// K3: per occupied cell, compress (core) or border attach (non-core) + counts
__global__ void k_cb(uint32_t* __restrict__ ws) {
  int i = blockIdx.x * 256 + threadIdx.x;
  if (i >= (int)ws[OFF_NOCC]) return;
  int cell = (int)ws[OFF_WL + i];
  const uint32_t* occ = ws + OFF_OCC;
  uint32_t* lab = ws + OFF_LAB;
  uint32_t* cnt = ws + OFF_CNT;
  int wi = cell >> 5, b = cell & 31, wx = wi & 15, y = cell >> 9;
  uint32_t cB = occ[wi];
  uint32_t lB = wx ? occ[wi - 1] : 0u;
  uint32_t rB = (wx < 15) ? occ[wi + 1] : 0u;
  uint32_t cA = 0, lA = 0, rA = 0, cC = 0, lC = 0, rC = 0;
  if (y > 0) { int w = wi - WPR; cA = occ[w]; lA = wx ? occ[w - 1] : 0u; rA = (wx < 15) ? occ[w + 1] : 0u; }
  if (y < GRIDW - 1) { int w = wi + WPR; cC = occ[w]; lC = wx ? occ[w - 1] : 0u; rC = (wx < 15) ? occ[w + 1] : 0u; }
  uint32_t hA0, hA1, hB0, hB1, hC0, hC1;
  hsum(lA, cA, rA, hA0, hA1); hsum(lB, cB, rB, hB0, hB1); hsum(lC, cC, rC, hC0, hC1);
  uint32_t cw0 = ge5(hA0, hA1, hB0, hB1, hC0, hC1) & cB;
  if ((cw0 >> b) & 1) {  // core: compress to final root, mark root, count
    uint32_t root = findc(lab, cell);
    lab[cell] = root;
    if (root == (uint32_t)cell) atomicOr(&ws[OFF_ROOTBM + wi], 1u << b);
    atomicAdd(&cnt[root], 1u);
  } else {               // border: min root among 8 core neighbors
    uint32_t m = NONE;
    bool t;
    t = (b > 0) ? (((cw0 >> (b - 1)) & 1) != 0) : (coreLbit(cA, lA, cB, lB, cC, lC) != 0);
    if (t) m = min(m, findc(lab, cell - 1));
    t = (b < 31) ? (((cw0 >> (b + 1)) & 1) != 0) : (coreRbit(cA, rA, cB, rB, cC, rC) != 0);
    if (t) m = min(m, findc(lab, cell + 1));
    if (y > 0) {
      uint32_t cZ = 0, lZ = 0, rZ = 0;
      if (y > 1) { int w = wi - 2 * WPR; cZ = occ[w]; lZ = wx ? occ[w - 1] : 0u; rZ = (wx < 15) ? occ[w + 1] : 0u; }
      uint32_t hZ0, hZ1;
      hsum(lZ, cZ, rZ, hZ0, hZ1);
      uint32_t cwm1 = ge5(hZ0, hZ1, hA0, hA1, hB0, hB1) & cA;
      if ((cwm1 >> b) & 1) m = min(m, findc(lab, cell - GRIDW));
      t = (b > 0) ? (((cwm1 >> (b - 1)) & 1) != 0) : (coreLbit(cZ, lZ, cA, lA, cB, lB) != 0);
      if (t) m = min(m, findc(lab, cell - GRIDW - 1));
      t = (b < 31) ? (((cwm1 >> (b + 1)) & 1) != 0) : (coreRbit(cZ, rZ, cA, rA, cB, rB) != 0);
      if (t) m = min(m, findc(lab, cell - GRIDW + 1));
    }
    if (y < GRIDW - 1) {
      uint32_t cD = 0, lD = 0, rD = 0;
      if (y < GRIDW - 2) { int w = wi + 2 * WPR; cD = occ[w]; lD = wx ? occ[w - 1] : 0u; rD = (wx < 15) ? occ[w + 1] : 0u; }
      uint32_t hD0, hD1;
      hsum(lD, cD, rD, hD0, hD1);
      uint32_t cw1 = ge5(hB0, hB1, hC0, hC1, hD0, hD1) & cC;
      if ((cw1 >> b) & 1) m = min(m, findc(lab, cell + GRIDW));
      t = (b > 0) ? (((cw1 >> (b - 1)) & 1) != 0) : (coreLbit(cB, lB, cC, lC, cD, lD) != 0);
      if (t) m = min(m, findc(lab, cell + GRIDW - 1));
      t = (b < 31) ? (((cw1 >> (b + 1)) & 1) != 0) : (coreRbit(cB, rB, cC, rC, cD, rD) != 0);
      if (t) m = min(m, findc(lab, cell + GRIDW + 1));
    }
    lab[cell] = m;  // NONE => noise; non-core cells are never UF parents
    if (m != NONE) atomicAdd(&cnt[m], 1u);
  }
}

// K4: dense root numbering (prefix over rootbm), keep filter, max kept id
__global__ void k_finish(uint32_t* __restrict__ ws, float* __restrict__ out,
                         int npts) {
  __shared__ uint32_t wsum[4];
  __shared__ int smax;
  int tid = threadIdx.x;
  if (tid == 0) smax = -1;
  int base = tid * 32;
  uint32_t s = 0;
  for (int j = 0; j < 32; j++) s += __popc(ws[OFF_ROOTBM + base + j]);
  int lane = tid & 63, wv = tid >> 6;
  uint32_t inc = s;
  for (int d = 1; d < 64; d <<= 1) { uint32_t t = __shfl_up(inc, d); if (lane >= d) inc += t; }
  if (lane == 63) wsum[wv] = inc;
  __syncthreads();
  uint32_t woff = 0;
  for (int k = 0; k < wv; k++) woff += wsum[k];
  uint32_t excl = woff + inc - s;
  int mx = -1;
  for (int j = 0; j < 32; j++) {
    uint32_t rbw = ws[OFF_ROOTBM + base + j];
    ws[OFF_RPRE + base + j] = excl;
    uint32_t rb = rbw, keep = 0;
    int d = (int)excl;
    while (rb) {
      int b2 = __ffs(rb) - 1; rb &= rb - 1;
      int r = (base + j) * 32 + b2;
      if (ws[OFF_CNT + r] >= 20u) { keep |= 1u << b2; mx = d; }
      d++;
    }
    ws[OFF_KEEPBM + base + j] = keep;
    excl += __popc(rbw);
  }
  if (mx >= 0) atomicMax(&smax, mx);
  __syncthreads();
  if (tid == 0) out[npts] = (float)(smax + 1);
}

// K5: scatter dense labels back to points
__global__ void k_scatter(const float* __restrict__ pts,
                          const uint32_t* __restrict__ ws,
                          float* __restrict__ out, int npts) {
  int i = blockIdx.x * 256 + threadIdx.x;
  if (i >= npts) return;
  float x = pts[i * 5 + 1];
  float y = pts[i * 5 + 2];
  int cx = (int)floorf((x - (-51.2f)) / 0.2f);  // identical math to k_vox
  int cy = (int)floorf((y - (-51.2f)) / 0.2f);
  cx = min(max(cx, 0), GRIDW - 1);
  cy = min(max(cy, 0), GRIDW - 1);
  int cell = cy * GRIDW + cx;
  uint32_t l = ws[OFF_LAB + cell];
  float o = -1.0f;
  if (l != NONE && ((ws[OFF_KEEPBM + (l >> 5)] >> (l & 31)) & 1)) {
    int dnum = ws[OFF_RPRE + (l >> 5)] +
               __popc(ws[OFF_ROOTBM + (l >> 5)] & ((1u << (l & 31)) - 1u));
    o = (float)dnum;
  }
  out[i] = o;
}

extern "C" void kernel_launch(void* const* d_in, const int* in_sizes, int n_in,
                              void* d_out, int out_size, void* d_ws, size_t ws_size,
                              hipStream_t stream) {
  const float* pts = (const float*)d_in[0];
  int npts = in_sizes[0] / 5;  // points are (N,5) float32
  uint32_t* ws = (uint32_t*)d_ws;
  float* out = (float*)d_out;
  int pblocks = (npts + 255) / 256;
  hipMemsetAsync(d_ws, 0, FILL_BYTES, stream);  // occ + rootbm + nOcc
  k_vox<<<pblocks, 256, 0, stream>>>(pts, ws, npts);
  k_merge<<<32, 256, 0, stream>>>(ws);
  k_cb<<<32, 256, 0, stream>>>(ws);
  k_finish<<<1, 256, 0, stream>>>(ws, out, npts);
  k_scatter<<<pblocks, 256, 0, stream>>>(pts, ws, out, npts);
}

// Round 10
// 104.262 us; speedup vs baseline: 1.2173x; 1.2173x over previous
//
#include <hip/hip_runtime.h>
#include <stdint.h>

// DBSCAN-on-voxel-grid, exact port of the JAX reference for batch_size==1.
// Grid 512x512, eps=1.5 => 8-connected adjacency, min_samples=5 (voxels,
// incl. self), clusters with <20 voxels dropped.
// R10: dense per-cell merge/cb (R6-style early-exit, coalesced) reading a
// PRECOMPUTED core-mask array; cell-id union-find (no rank scan, R8-proven);
// lazy lab/cnt init in k_vox (R9-proven); finish fused into scatter (each of
// 32 blocks redoes the tiny root prefix in LDS). 6 dispatches.
// Note: harness ws-poison (~40us, 268MB fill) is inside the timed window —
// fixed floor we cannot touch.

#define GRIDW 512
#define WPR 16        // bitmap words per row
#define NWORDS 8192   // 512*512/32
#define NCELLS 262144
#define NONE 0xFFFFFFFFu

// ---- ws layout (uint32 units) ----
#define OFF_OCC    0       // 8192  (zeroed by memset)
#define OFF_ROOTBM 8192    // 8192  (zeroed in k_cm; bit per cell)
#define OFF_CM     16384   // 8192  (written in k_cm)
#define OFF_LAB    24576   // 262144 (occupied entries lazy-init in k_vox)
#define OFF_CNT    286720  // 262144 (occupied entries lazy-zeroed in k_vox)
#define FILL_BYTES (NWORDS * 4)

// per-position horizontal (west+self+east) 2-bit counts for a row of 32 cells
__device__ __forceinline__ void hsum(uint32_t l, uint32_t c, uint32_t r,
                                     uint32_t& h0, uint32_t& h1) {
  uint32_t Wb = (c << 1) | (l >> 31);
  uint32_t Eb = (c >> 1) | (r << 31);
  h0 = Wb ^ c ^ Eb;
  h1 = (Wb & c) | (Eb & (Wb ^ c));
}

// per-position (sum of three 2-bit row counts) >= 5 (bit-sliced adders)
__device__ __forceinline__ uint32_t ge5(uint32_t a0, uint32_t a1, uint32_t b0,
                                        uint32_t b1, uint32_t c0, uint32_t c1) {
  uint32_t u0 = a0 ^ b0, cy = a0 & b0;
  uint32_t t = a1 ^ b1;
  uint32_t u1 = t ^ cy;
  uint32_t u2 = (a1 & b1) | (cy & t);
  uint32_t v0 = u0 ^ c0, k0 = u0 & c0;
  uint32_t t2 = u1 ^ c1;
  uint32_t v1 = t2 ^ k0;
  uint32_t k1 = (u1 & c1) | (k0 & t2);
  uint32_t v2 = u2 ^ k1;
  uint32_t v3 = u2 & k1;
  return v3 | (v2 & (v1 | v0));  // count in {5..9}
}

__device__ __forceinline__ uint32_t aread(uint32_t* p) {
  return __hip_atomic_load(p, __ATOMIC_RELAXED, __HIP_MEMORY_SCOPE_AGENT);
}

// find root with guarded path compression: links only ever DECREASE
// (monotone invariant => no cycles, guaranteed termination).
__device__ __forceinline__ uint32_t findc(uint32_t* L, uint32_t x) {
  uint32_t r = x, p = aread(&L[r]);
  while (p != r) { r = p; p = aread(&L[r]); }
  while (x > r) {
    uint32_t nx = aread(&L[x]);
    if (nx <= r) break;
    atomicCAS(&L[x], nx, r);  // best effort, only writes a smaller value
    x = nx;
  }
  return r;
}

// link larger root under smaller => final root == min core CELL of component
__device__ __forceinline__ void unite(uint32_t* L, uint32_t a, uint32_t b) {
  for (;;) {
    a = findc(L, a);
    b = findc(L, b);
    if (a == b) return;
    uint32_t lo = min(a, b), hi = max(a, b);
    if (atomicCAS(&L[hi], hi, lo) == hi) return;
    a = lo; b = hi;
  }
}

// K1: voxelize; the unique setter of each occupancy bit lazily inits lab/cnt
__global__ void k_vox(const float* __restrict__ pts, uint32_t* __restrict__ ws,
                      int npts) {
  int i = blockIdx.x * 256 + threadIdx.x;
  if (i >= npts) return;
  float x = pts[i * 5 + 1];
  float y = pts[i * 5 + 2];
  int cx = (int)floorf((x - (-51.2f)) / 0.2f);  // identical f32 ops to jnp
  int cy = (int)floorf((y - (-51.2f)) / 0.2f);
  cx = min(max(cx, 0), GRIDW - 1);
  cy = min(max(cy, 0), GRIDW - 1);
  int cell = cy * GRIDW + cx;
  uint32_t old = atomicOr(&ws[OFF_OCC + (cell >> 5)], 1u << (cell & 31));
  if (!((old >> (cell & 31)) & 1)) {
    ws[OFF_LAB + cell] = (uint32_t)cell;
    ws[OFF_CNT + cell] = 0u;
  }
}

// K2: per-word core mask from 3x3 SWAR counts; also zero rootbm
__global__ void k_cm(uint32_t* __restrict__ ws) {
  int wi = blockIdx.x * 256 + threadIdx.x;  // 32 blocks x 256 = 8192 words
  const uint32_t* occ = ws + OFF_OCC;
  ws[OFF_ROOTBM + wi] = 0u;
  uint32_t cB = occ[wi];
  int y = wi >> 4, wx = wi & 15;
  uint32_t lB = wx ? occ[wi - 1] : 0u;
  uint32_t rB = (wx < 15) ? occ[wi + 1] : 0u;
  uint32_t cA = 0, lA = 0, rA = 0, cC = 0, lC = 0, rC = 0;
  if (y > 0) { int w = wi - WPR; cA = occ[w]; lA = wx ? occ[w - 1] : 0u; rA = (wx < 15) ? occ[w + 1] : 0u; }
  if (y < GRIDW - 1) { int w = wi + WPR; cC = occ[w]; lC = wx ? occ[w - 1] : 0u; rC = (wx < 15) ? occ[w + 1] : 0u; }
  uint32_t a0, a1, b0, b1, c0, c1;
  hsum(lA, cA, rA, a0, a1); hsum(lB, cB, rB, b0, b1); hsum(lC, cC, rC, c0, c1);
  ws[OFF_CM + wi] = ge5(a0, a1, b0, b1, c0, c1) & cB;
}

// K3: per-cell union of core-core edges (E, S, SE, SW) — cm loads only
__global__ void k_merge(uint32_t* __restrict__ ws) {
  int cell = blockIdx.x * 256 + threadIdx.x;
  const uint32_t* cm = ws + OFF_CM;
  uint32_t* lab = ws + OFF_LAB;
  int wi = cell >> 5, b = cell & 31, wx = wi & 15, y = cell >> 9;
  uint32_t cw0 = cm[wi];
  if (!((cw0 >> b) & 1)) return;  // not a core cell
  bool eC = (b < 31) ? (((cw0 >> (b + 1)) & 1) != 0)
                     : ((wx < 15) ? ((cm[wi + 1] & 1u) != 0) : false);
  if (eC) unite(lab, cell, cell + 1);
  if (y < GRIDW - 1) {
    uint32_t cmS = cm[wi + WPR];
    if ((cmS >> b) & 1) unite(lab, cell, cell + GRIDW);
    bool seC = (b < 31) ? (((cmS >> (b + 1)) & 1) != 0)
                        : ((wx < 15) ? ((cm[wi + WPR + 1] & 1u) != 0) : false);
    if (seC) unite(lab, cell, cell + GRIDW + 1);
    bool swC = (b > 0) ? (((cmS >> (b - 1)) & 1) != 0)
                       : ((wx > 0) ? ((cm[wi + WPR - 1] >> 31) != 0) : false);
    if (swC) unite(lab, cell, cell + GRIDW - 1);
  }
}

// K4: per-cell compress (core) or border attach (non-core) + voxel counts
__global__ void k_cb(uint32_t* __restrict__ ws) {
  int cell = blockIdx.x * 256 + threadIdx.x;
  const uint32_t* occ = ws + OFF_OCC;
  const uint32_t* cm = ws + OFF_CM;
  uint32_t* lab = ws + OFF_LAB;
  uint32_t* cnt = ws + OFF_CNT;
  int wi = cell >> 5, b = cell & 31, wx = wi & 15, y = cell >> 9;
  if (!((occ[wi] >> b) & 1)) return;  // unoccupied
  uint32_t cw0 = cm[wi];
  if ((cw0 >> b) & 1) {  // core: compress to final root, mark root, count
    uint32_t root = findc(lab, cell);
    lab[cell] = root;
    if (root == (uint32_t)cell) atomicOr(&ws[OFF_ROOTBM + wi], 1u << b);
    atomicAdd(&cnt[root], 1u);
  } else {               // border: min root among 8 core neighbors
    uint32_t m = NONE;
    bool t;
    t = (b > 0) ? (((cw0 >> (b - 1)) & 1) != 0)
                : ((wx > 0) ? ((cm[wi - 1] >> 31) != 0) : false);
    if (t) m = min(m, findc(lab, cell - 1));
    t = (b < 31) ? (((cw0 >> (b + 1)) & 1) != 0)
                 : ((wx < 15) ? ((cm[wi + 1] & 1u) != 0) : false);
    if (t) m = min(m, findc(lab, cell + 1));
    if (y > 0) {
      uint32_t cmN = cm[wi - WPR];
      if ((cmN >> b) & 1) m = min(m, findc(lab, cell - GRIDW));
      t = (b > 0) ? (((cmN >> (b - 1)) & 1) != 0)
                  : ((wx > 0) ? ((cm[wi - WPR - 1] >> 31) != 0) : false);
      if (t) m = min(m, findc(lab, cell - GRIDW - 1));
      t = (b < 31) ? (((cmN >> (b + 1)) & 1) != 0)
                   : ((wx < 15) ? ((cm[wi - WPR + 1] & 1u) != 0) : false);
      if (t) m = min(m, findc(lab, cell - GRIDW + 1));
    }
    if (y < GRIDW - 1) {
      uint32_t cmS = cm[wi + WPR];
      if ((cmS >> b) & 1) m = min(m, findc(lab, cell + GRIDW));
      t = (b > 0) ? (((cmS >> (b - 1)) & 1) != 0)
                  : ((wx > 0) ? ((cm[wi + WPR - 1] >> 31) != 0) : false);
      if (t) m = min(m, findc(lab, cell + GRIDW - 1));
      t = (b < 31) ? (((cmS >> (b + 1)) & 1) != 0)
                   : ((wx < 15) ? ((cm[wi + WPR + 1] & 1u) != 0) : false);
      if (t) m = min(m, findc(lab, cell + GRIDW + 1));
    }
    lab[cell] = m;  // NONE => noise; non-core cells are never UF parents
    if (m != NONE) atomicAdd(&cnt[m], 1u);
  }
}

// K5: fused finish+scatter. Each block independently builds the dense-root
// prefix + keep bitmap in LDS (tiny), then scatters its points.
__global__ __launch_bounds__(256) void k_scatter(
    const float* __restrict__ pts, uint32_t* __restrict__ ws,
    float* __restrict__ out, int npts) {
  __shared__ uint32_t rpre_s[NWORDS];   // 32 KB: excl. root-rank prefix/word
  __shared__ uint32_t keep_s[NWORDS];   // 32 KB: keep bitmap
  __shared__ uint32_t wsum[4];
  __shared__ int smax;
  int tid = threadIdx.x;
  if (tid == 0) smax = -1;
  int base = tid * 32;
  uint32_t s = 0;
  for (int j = 0; j < 32; j++) s += __popc(ws[OFF_ROOTBM + base + j]);
  int lane = tid & 63, wv = tid >> 6;
  uint32_t inc = s;
  for (int d = 1; d < 64; d <<= 1) { uint32_t t = __shfl_up(inc, d); if (lane >= d) inc += t; }
  if (lane == 63) wsum[wv] = inc;
  __syncthreads();
  uint32_t woff = 0;
  for (int k = 0; k < wv; k++) woff += wsum[k];
  uint32_t excl = woff + inc - s;
  int mx = -1;
  for (int j = 0; j < 32; j++) {
    uint32_t rbw = ws[OFF_ROOTBM + base + j];
    rpre_s[base + j] = excl;
    uint32_t rb = rbw, keep = 0;
    int d = (int)excl;
    while (rb) {
      int b2 = __ffs(rb) - 1; rb &= rb - 1;
      int r = (base + j) * 32 + b2;
      if (ws[OFF_CNT + r] >= 20u) { keep |= 1u << b2; mx = d; }
      d++;
    }
    keep_s[base + j] = keep;
    excl += __popc(rbw);
  }
  if (mx >= 0) atomicMax(&smax, mx);
  __syncthreads();
  // scatter this block's points
  int i = blockIdx.x * 256 + tid;
  if (i < npts) {
    float x = pts[i * 5 + 1];
    float y = pts[i * 5 + 2];
    int cx = (int)floorf((x - (-51.2f)) / 0.2f);  // identical math to k_vox
    int cy = (int)floorf((y - (-51.2f)) / 0.2f);
    cx = min(max(cx, 0), GRIDW - 1);
    cy = min(max(cy, 0), GRIDW - 1);
    int cell = cy * GRIDW + cx;
    uint32_t l = ws[OFF_LAB + cell];
    float o = -1.0f;
    if (l != NONE && ((keep_s[l >> 5] >> (l & 31)) & 1)) {
      int dnum = rpre_s[l >> 5] +
                 __popc(ws[OFF_ROOTBM + (l >> 5)] & ((1u << (l & 31)) - 1u));
      o = (float)dnum;
    }
    out[i] = o;
  }
  if (tid == 0) out[npts] = (float)(smax + 1);  // same value from every block
}

extern "C" void kernel_launch(void* const* d_in, const int* in_sizes, int n_in,
                              void* d_out, int out_size, void* d_ws, size_t ws_size,
                              hipStream_t stream) {
  const float* pts = (const float*)d_in[0];
  int npts = in_sizes[0] / 5;  // points are (N,5) float32
  uint32_t* ws = (uint32_t*)d_ws;
  float* out = (float*)d_out;
  int pblocks = (npts + 255) / 256;
  hipMemsetAsync(d_ws, 0, FILL_BYTES, stream);  // occ only
  k_vox<<<pblocks, 256, 0, stream>>>(pts, ws, npts);
  k_cm<<<NWORDS / 256, 256, 0, stream>>>(ws);
  k_merge<<<NCELLS / 256, 256, 0, stream>>>(ws);
  k_cb<<<NCELLS / 256, 256, 0, stream>>>(ws);
  k_scatter<<<pblocks, 256, 0, stream>>>(pts, ws, out, npts);
}